// Round 1
// baseline (1681.927 us; speedup 1.0000x reference)
//
#include <hip/hip_runtime.h>
#include <cfloat>

#define N_ROWS 65536
#define DIM 256
#define K_CODES 2048
#define MT 128     // rows per block
#define KT 256     // codes per k-tile
#define DC 16      // d-chunk staged in LDS
#define BLOCK 256
#define ZSTR (MT + 4)      // 132 floats, keeps 16B align (132*4=528=33*16)
#define ESTR (KT + 4)      // 260 floats, 16B-mult keeps b128 align
#define NSTAGES ((DIM / DC) * (K_CODES / KT))   // 128

// ---------------- e_sq precompute: one wave per code ----------------
__global__ __launch_bounds__(256)
void vq_esq_kernel(const float* __restrict__ emb, float* __restrict__ esq) {
    int w = threadIdx.x >> 6;
    int lane = threadIdx.x & 63;
    int k = blockIdx.x * 4 + w;
    float4 v = *(const float4*)&emb[(size_t)k * DIM + lane * 4];
    float s = v.x * v.x + v.y * v.y + v.z * v.z + v.w * v.w;
    #pragma unroll
    for (int off = 32; off >= 1; off >>= 1) s += __shfl_xor(s, off, 64);
    if (lane == 0) esq[k] = s;
}

// ---------------- main fused kernel (16x8 register tile) --------
// Thread (rg,cg) owns rows {16rg..16rg+15} x codes {kt+4cg+i} u {kt+128+4cg+i}.
// Per d: 4 broadcast a-reads + 2 contiguous b-reads (b128) feed 128 FMAs
// (21.3 FMA-instr per ds_read_b128 vs 16 in the 8x8 tile -> LDS pipe off
// the critical path sooner). One barrier per stage; global prefetch for
// stage s+1 issued before the 2048-FMA compute of stage s, LDS writes after.
__global__ __launch_bounds__(BLOCK, 2)
void vq_main_kernel(const float* __restrict__ z,
                    const float* __restrict__ emb,
                    const float* __restrict__ esq,
                    float* __restrict__ out,
                    float* __restrict__ loss_acc) {
    __shared__ float zS[2][DC][ZSTR];
    __shared__ float eT[2][DC][ESTR];
    __shared__ float zsq_s[MT];
    __shared__ int   best_s[MT];
    __shared__ float lred[4];

    const int tid = threadIdx.x;
    const int m0  = blockIdx.x * MT;
    const int rg  = tid >> 5;   // 0..7  : rows 16*rg..16*rg+15
    const int cg  = tid & 31;   // 0..31 : codes 4*cg(+128)
    const int esr = tid >> 2;   // eT staging code base (0..63)
    const int esf = tid & 3;    // eT staging float4 slot in d-chunk
    const int zr  = tid >> 1;   // zS staging row (0..127)
    const int zh  = tid & 1;    // zS staging d-half (8 floats)

    // ---- z_sq for the block's 128 rows (2 threads/row; combine tree is
    //      bit-identical to the verified kernel: (s0+s2)+(s1+s3)) ----
    {
        const float* zp = &z[(size_t)(m0 + zr) * DIM + zh * 64];
        float sA = 0.f, sB = 0.f;
        #pragma unroll
        for (int d4 = 0; d4 < 16; ++d4) {
            float4 v = *(const float4*)&zp[d4 * 4];
            sA += v.x * v.x; sA += v.y * v.y; sA += v.z * v.z; sA += v.w * v.w;
        }
        #pragma unroll
        for (int d4 = 0; d4 < 16; ++d4) {
            float4 v = *(const float4*)&zp[128 + d4 * 4];
            sB += v.x * v.x; sB += v.y * v.y; sB += v.z * v.z; sB += v.w * v.w;
        }
        float s = sA + sB;              // lane even: s0+s2, lane odd: s1+s3
        s += __shfl_down(s, 1, 64);     // (s0+s2)+(s1+s3)
        if (zh == 0) zsq_s[zr] = s;
    }

    // ---- stage 0 into buffer 0 ----
    {
        const float* zp = &z[(size_t)(m0 + zr) * DIM + 8 * zh];
        float4 za = *(const float4*)&zp[0];
        float4 zb = *(const float4*)&zp[4];
        zS[0][8 * zh + 0][zr] = za.x;
        zS[0][8 * zh + 1][zr] = za.y;
        zS[0][8 * zh + 2][zr] = za.z;
        zS[0][8 * zh + 3][zr] = za.w;
        zS[0][8 * zh + 4][zr] = zb.x;
        zS[0][8 * zh + 5][zr] = zb.y;
        zS[0][8 * zh + 6][zr] = zb.z;
        zS[0][8 * zh + 7][zr] = zb.w;
        #pragma unroll
        for (int cb = 0; cb < 4; ++cb) {
            int c = esr + cb * 64;
            float4 ev = *(const float4*)&emb[(size_t)c * DIM + 4 * esf];
            eT[0][4 * esf + 0][c] = ev.x;
            eT[0][4 * esf + 1][c] = ev.y;
            eT[0][4 * esf + 2][c] = ev.z;
            eT[0][4 * esf + 3][c] = ev.w;
        }
    }
    __syncthreads();

    float bestv[16];
    int   besti[16];
    #pragma unroll
    for (int j = 0; j < 16; ++j) { bestv[j] = FLT_MAX; besti[j] = 0; }

    float acc[16][8];

    for (int s = 0; s < NSTAGES; ++s) {
        const int p     = s & 1;
        const int kt    = (s >> 4) * KT;
        const int dcIdx = s & 15;

        if (dcIdx == 0) {
            #pragma unroll
            for (int j = 0; j < 16; ++j)
                #pragma unroll
                for (int i = 0; i < 8; ++i) acc[j][i] = 0.f;
        }

        // ---- prefetch stage s+1 (global -> regs); uniform clamp on last ----
        const int sn  = (s + 1 < NSTAGES) ? s + 1 : s;
        const int nkt = (sn >> 4) * KT;
        const int ndc = (sn & 15) * DC;
        float4 zn0 = *(const float4*)&z[(size_t)(m0 + zr) * DIM + ndc + 8 * zh];
        float4 zn1 = *(const float4*)&z[(size_t)(m0 + zr) * DIM + ndc + 8 * zh + 4];
        float4 en0 = *(const float4*)&emb[(size_t)(nkt + esr +   0) * DIM + ndc + 4 * esf];
        float4 en1 = *(const float4*)&emb[(size_t)(nkt + esr +  64) * DIM + ndc + 4 * esf];
        float4 en2 = *(const float4*)&emb[(size_t)(nkt + esr + 128) * DIM + ndc + 4 * esf];
        float4 en3 = *(const float4*)&emb[(size_t)(nkt + esr + 192) * DIM + ndc + 4 * esf];

        // ---- compute stage s ----
        #pragma unroll
        for (int d = 0; d < DC; ++d) {
            float4 a0 = *(const float4*)&zS[p][d][16 * rg];
            float4 a1 = *(const float4*)&zS[p][d][16 * rg + 4];
            float4 a2 = *(const float4*)&zS[p][d][16 * rg + 8];
            float4 a3 = *(const float4*)&zS[p][d][16 * rg + 12];
            float4 b0 = *(const float4*)&eT[p][d][4 * cg];
            float4 b1 = *(const float4*)&eT[p][d][128 + 4 * cg];
            float a[16] = {a0.x, a0.y, a0.z, a0.w, a1.x, a1.y, a1.z, a1.w,
                           a2.x, a2.y, a2.z, a2.w, a3.x, a3.y, a3.z, a3.w};
            float b[8]  = {b0.x, b0.y, b0.z, b0.w, b1.x, b1.y, b1.z, b1.w};
            #pragma unroll
            for (int j = 0; j < 16; ++j)
                #pragma unroll
                for (int i = 0; i < 8; ++i)
                    acc[j][i] = fmaf(a[j], b[i], acc[j][i]);
        }

        // ---- write prefetched stage into the other buffer ----
        {
            const int q = p ^ 1;
            zS[q][8 * zh + 0][zr] = zn0.x;
            zS[q][8 * zh + 1][zr] = zn0.y;
            zS[q][8 * zh + 2][zr] = zn0.z;
            zS[q][8 * zh + 3][zr] = zn0.w;
            zS[q][8 * zh + 4][zr] = zn1.x;
            zS[q][8 * zh + 5][zr] = zn1.y;
            zS[q][8 * zh + 6][zr] = zn1.z;
            zS[q][8 * zh + 7][zr] = zn1.w;
            eT[q][4 * esf + 0][esr      ] = en0.x;
            eT[q][4 * esf + 1][esr      ] = en0.y;
            eT[q][4 * esf + 2][esr      ] = en0.z;
            eT[q][4 * esf + 3][esr      ] = en0.w;
            eT[q][4 * esf + 0][esr +  64] = en1.x;
            eT[q][4 * esf + 1][esr +  64] = en1.y;
            eT[q][4 * esf + 2][esr +  64] = en1.z;
            eT[q][4 * esf + 3][esr +  64] = en1.w;
            eT[q][4 * esf + 0][esr + 128] = en2.x;
            eT[q][4 * esf + 1][esr + 128] = en2.y;
            eT[q][4 * esf + 2][esr + 128] = en2.z;
            eT[q][4 * esf + 3][esr + 128] = en2.w;
            eT[q][4 * esf + 0][esr + 192] = en3.x;
            eT[q][4 * esf + 1][esr + 192] = en3.y;
            eT[q][4 * esf + 2][esr + 192] = en3.z;
            eT[q][4 * esf + 3][esr + 192] = en3.w;
        }

        // ---- end of k-tile: literal f32 distance + running argmin ----
        if (dcIdx == 15) {
            float4 e0 = *(const float4*)&esq[kt + 4 * cg];
            float4 e1 = *(const float4*)&esq[kt + 128 + 4 * cg];
            float es[8] = {e0.x, e0.y, e0.z, e0.w, e1.x, e1.y, e1.z, e1.w};
            #pragma unroll
            for (int j = 0; j < 16; ++j) {
                float zs = zsq_s[16 * rg + j];
                #pragma unroll
                for (int i = 0; i < 8; ++i) {
                    float t    = zs + es[i];             // fl(z_sq + e_sq)
                    float dist = t - 2.0f * acc[j][i];   // fl(t - 2*cross)
                    int idx = (i < 4) ? (kt + 4 * cg + i) : (kt + 128 + 4 * cg + (i - 4));
                    bool better = (dist < bestv[j]);
                    bestv[j] = better ? dist : bestv[j];
                    besti[j] = better ? idx  : besti[j];
                }
            }
        }
        __syncthreads();
    }

    // cross-lane argmin over the 32 code-group lanes (lexicographic: val, idx)
    #pragma unroll
    for (int off = 16; off >= 1; off >>= 1) {
        #pragma unroll
        for (int j = 0; j < 16; ++j) {
            float ov = __shfl_xor(bestv[j], off, 64);
            int   oi = __shfl_xor(besti[j], off, 64);
            bool take = (ov < bestv[j]) || (ov == bestv[j] && oi < besti[j]);
            bestv[j] = take ? ov : bestv[j];
            besti[j] = take ? oi : besti[j];
        }
    }
    if (cg == 0) {
        #pragma unroll
        for (int j = 0; j < 16; ++j) best_s[16 * rg + j] = besti[j];
    }
    __syncthreads();

    // ---- epilogue: z_q_st (straight-through), loss partial, indices ----
    float lsum = 0.f;
    const int d4 = tid & 63;
    for (int it = 0; it < 32; ++it) {
        int r  = (tid >> 6) + it * 4;
        int bk = best_s[r];
        float4 q4 = *(const float4*)&emb[(size_t)bk * DIM + 4 * d4];
        float4 z4 = *(const float4*)&z[(size_t)(m0 + r) * DIM + 4 * d4];
        float4 o;
        float dx;
        dx = q4.x - z4.x; o.x = z4.x + dx; lsum = fmaf(dx, dx, lsum);
        dx = q4.y - z4.y; o.y = z4.y + dx; lsum = fmaf(dx, dx, lsum);
        dx = q4.z - z4.z; o.z = z4.z + dx; lsum = fmaf(dx, dx, lsum);
        dx = q4.w - z4.w; o.w = z4.w + dx; lsum = fmaf(dx, dx, lsum);
        *(float4*)&out[(size_t)(m0 + r) * DIM + 4 * d4] = o;
    }
    #pragma unroll
    for (int off = 32; off >= 1; off >>= 1) lsum += __shfl_xor(lsum, off, 64);
    if ((tid & 63) == 0) lred[tid >> 6] = lsum;
    __syncthreads();
    if (tid == 0) {
        float bs = lred[0] + lred[1] + lred[2] + lred[3];
        atomicAdd(loss_acc, bs);
    }
    // indices as float32 values
    if (tid < MT) out[(size_t)N_ROWS * DIM + 1 + m0 + tid] = (float)best_s[tid];
}

// ---------------- finalize: vq_loss = 1.25 * mean ----------------
__global__ void vq_finalize_kernel(const float* __restrict__ loss_acc,
                                   float* __restrict__ out) {
    double s = (double)loss_acc[0];
    out[(size_t)N_ROWS * DIM] = (float)(s * 1.25 / ((double)N_ROWS * (double)DIM));
}

extern "C" void kernel_launch(void* const* d_in, const int* in_sizes, int n_in,
                              void* d_out, int out_size, void* d_ws, size_t ws_size,
                              hipStream_t stream) {
    (void)in_sizes; (void)n_in; (void)out_size; (void)ws_size;
    const float* z   = (const float*)d_in[0];
    const float* emb = (const float*)d_in[1];
    float* out = (float*)d_out;
    float* ws  = (float*)d_ws;
    float* loss_acc = ws;        // ws[0]
    float* esq      = ws + 64;   // 2048 floats

    hipMemsetAsync(d_ws, 0, sizeof(float), stream);
    vq_esq_kernel<<<K_CODES / 4, 256, 0, stream>>>(emb, esq);
    vq_main_kernel<<<N_ROWS / MT, BLOCK, 0, stream>>>(z, emb, esq, out, loss_acc);
    vq_finalize_kernel<<<1, 1, 0, stream>>>(loss_acc, out);
}

// Round 2
// 1102.648 us; speedup vs baseline: 1.5254x; 1.5254x over previous
//
#include <hip/hip_runtime.h>
#include <cfloat>

#define N_ROWS 65536
#define DIM 256
#define K_CODES 2048
#define MT 128     // rows per block
#define KT 256     // codes per k-tile
#define DC 16      // d-chunk staged in LDS
#define BLOCK 256
#define ZSTR (MT + 4)      // 132 floats, keeps 16B align
#define ESTR (KT + 4)      // 260 floats, 16B-mult keeps b128 align
#define NSTAGES ((DIM / DC) * (K_CODES / KT))   // 128

// ---------------- e_sq precompute: one wave per code ----------------
__global__ __launch_bounds__(256)
void vq_esq_kernel(const float* __restrict__ emb, float* __restrict__ esq) {
    int w = threadIdx.x >> 6;
    int lane = threadIdx.x & 63;
    int k = blockIdx.x * 4 + w;
    float4 v = *(const float4*)&emb[(size_t)k * DIM + lane * 4];
    float s = v.x * v.x + v.y * v.y + v.z * v.z + v.w * v.w;
    #pragma unroll
    for (int off = 32; off >= 1; off >>= 1) s += __shfl_xor(s, off, 64);
    if (lane == 0) esq[k] = s;
}

// ---------------- main fused kernel (16x8 register tile) --------
// R1 fix vs R0: launch_bounds minwaves 2 -> 1 (R0's "2" resolved to a
// 128-VGPR cap and spilled acc[16][8] to scratch: 4.3 GB HBM writes).
// Compute split into two 8-row halves to cut transient VGPR pressure;
// per-accumulator FMA chain order over d unchanged (bit-identical).
__global__ __launch_bounds__(BLOCK, 1)
void vq_main_kernel(const float* __restrict__ z,
                    const float* __restrict__ emb,
                    const float* __restrict__ esq,
                    float* __restrict__ out,
                    float* __restrict__ loss_acc) {
    __shared__ float zS[2][DC][ZSTR];
    __shared__ float eT[2][DC][ESTR];
    __shared__ float zsq_s[MT];
    __shared__ int   best_s[MT];
    __shared__ float lred[4];

    const int tid = threadIdx.x;
    const int m0  = blockIdx.x * MT;
    const int rg  = tid >> 5;   // 0..7  : rows 16*rg..16*rg+15
    const int cg  = tid & 31;   // 0..31 : codes 4*cg(+128)
    const int esr = tid >> 2;   // eT staging code base (0..63)
    const int esf = tid & 3;    // eT staging float4 slot in d-chunk
    const int zr  = tid >> 1;   // zS staging row (0..127)
    const int zh  = tid & 1;    // zS staging d-half (8 floats)

    // ---- z_sq for the block's 128 rows (2 threads/row; combine tree is
    //      bit-identical to the verified kernel: (s0+s2)+(s1+s3)) ----
    {
        const float* zp = &z[(size_t)(m0 + zr) * DIM + zh * 64];
        float sA = 0.f, sB = 0.f;
        #pragma unroll
        for (int d4 = 0; d4 < 16; ++d4) {
            float4 v = *(const float4*)&zp[d4 * 4];
            sA += v.x * v.x; sA += v.y * v.y; sA += v.z * v.z; sA += v.w * v.w;
        }
        #pragma unroll
        for (int d4 = 0; d4 < 16; ++d4) {
            float4 v = *(const float4*)&zp[128 + d4 * 4];
            sB += v.x * v.x; sB += v.y * v.y; sB += v.z * v.z; sB += v.w * v.w;
        }
        float s = sA + sB;              // lane even: s0+s2, lane odd: s1+s3
        s += __shfl_down(s, 1, 64);     // (s0+s2)+(s1+s3)
        if (zh == 0) zsq_s[zr] = s;
    }

    // ---- stage 0 into buffer 0 ----
    {
        const float* zp = &z[(size_t)(m0 + zr) * DIM + 8 * zh];
        float4 za = *(const float4*)&zp[0];
        float4 zb = *(const float4*)&zp[4];
        zS[0][8 * zh + 0][zr] = za.x;
        zS[0][8 * zh + 1][zr] = za.y;
        zS[0][8 * zh + 2][zr] = za.z;
        zS[0][8 * zh + 3][zr] = za.w;
        zS[0][8 * zh + 4][zr] = zb.x;
        zS[0][8 * zh + 5][zr] = zb.y;
        zS[0][8 * zh + 6][zr] = zb.z;
        zS[0][8 * zh + 7][zr] = zb.w;
        #pragma unroll
        for (int cb = 0; cb < 4; ++cb) {
            int c = esr + cb * 64;
            float4 ev = *(const float4*)&emb[(size_t)c * DIM + 4 * esf];
            eT[0][4 * esf + 0][c] = ev.x;
            eT[0][4 * esf + 1][c] = ev.y;
            eT[0][4 * esf + 2][c] = ev.z;
            eT[0][4 * esf + 3][c] = ev.w;
        }
    }
    __syncthreads();

    float bestv[16];
    int   besti[16];
    #pragma unroll
    for (int j = 0; j < 16; ++j) { bestv[j] = FLT_MAX; besti[j] = 0; }

    float acc[16][8];

    for (int s = 0; s < NSTAGES; ++s) {
        const int p     = s & 1;
        const int kt    = (s >> 4) * KT;
        const int dcIdx = s & 15;

        if (dcIdx == 0) {
            #pragma unroll
            for (int j = 0; j < 16; ++j)
                #pragma unroll
                for (int i = 0; i < 8; ++i) acc[j][i] = 0.f;
        }

        // ---- prefetch stage s+1 (global -> regs); uniform clamp on last ----
        const int sn  = (s + 1 < NSTAGES) ? s + 1 : s;
        const int nkt = (sn >> 4) * KT;
        const int ndc = (sn & 15) * DC;
        float4 zn0 = *(const float4*)&z[(size_t)(m0 + zr) * DIM + ndc + 8 * zh];
        float4 zn1 = *(const float4*)&z[(size_t)(m0 + zr) * DIM + ndc + 8 * zh + 4];
        float4 en0 = *(const float4*)&emb[(size_t)(nkt + esr +   0) * DIM + ndc + 4 * esf];
        float4 en1 = *(const float4*)&emb[(size_t)(nkt + esr +  64) * DIM + ndc + 4 * esf];
        float4 en2 = *(const float4*)&emb[(size_t)(nkt + esr + 128) * DIM + ndc + 4 * esf];
        float4 en3 = *(const float4*)&emb[(size_t)(nkt + esr + 192) * DIM + ndc + 4 * esf];

        // ---- compute stage s (two 8-row halves -> lower transient VGPRs) ----
        #pragma unroll
        for (int d = 0; d < DC; ++d) {
            float4 b0 = *(const float4*)&eT[p][d][4 * cg];
            float4 b1 = *(const float4*)&eT[p][d][128 + 4 * cg];
            float b[8]  = {b0.x, b0.y, b0.z, b0.w, b1.x, b1.y, b1.z, b1.w};
            {
                float4 a0 = *(const float4*)&zS[p][d][16 * rg];
                float4 a1 = *(const float4*)&zS[p][d][16 * rg + 4];
                float a[8] = {a0.x, a0.y, a0.z, a0.w, a1.x, a1.y, a1.z, a1.w};
                #pragma unroll
                for (int j = 0; j < 8; ++j)
                    #pragma unroll
                    for (int i = 0; i < 8; ++i)
                        acc[j][i] = fmaf(a[j], b[i], acc[j][i]);
            }
            {
                float4 a2 = *(const float4*)&zS[p][d][16 * rg + 8];
                float4 a3 = *(const float4*)&zS[p][d][16 * rg + 12];
                float a[8] = {a2.x, a2.y, a2.z, a2.w, a3.x, a3.y, a3.z, a3.w};
                #pragma unroll
                for (int j = 0; j < 8; ++j)
                    #pragma unroll
                    for (int i = 0; i < 8; ++i)
                        acc[8 + j][i] = fmaf(a[j], b[i], acc[8 + j][i]);
            }
        }

        // ---- write prefetched stage into the other buffer ----
        {
            const int q = p ^ 1;
            zS[q][8 * zh + 0][zr] = zn0.x;
            zS[q][8 * zh + 1][zr] = zn0.y;
            zS[q][8 * zh + 2][zr] = zn0.z;
            zS[q][8 * zh + 3][zr] = zn0.w;
            zS[q][8 * zh + 4][zr] = zn1.x;
            zS[q][8 * zh + 5][zr] = zn1.y;
            zS[q][8 * zh + 6][zr] = zn1.z;
            zS[q][8 * zh + 7][zr] = zn1.w;
            eT[q][4 * esf + 0][esr      ] = en0.x;
            eT[q][4 * esf + 1][esr      ] = en0.y;
            eT[q][4 * esf + 2][esr      ] = en0.z;
            eT[q][4 * esf + 3][esr      ] = en0.w;
            eT[q][4 * esf + 0][esr +  64] = en1.x;
            eT[q][4 * esf + 1][esr +  64] = en1.y;
            eT[q][4 * esf + 2][esr +  64] = en1.z;
            eT[q][4 * esf + 3][esr +  64] = en1.w;
            eT[q][4 * esf + 0][esr + 128] = en2.x;
            eT[q][4 * esf + 1][esr + 128] = en2.y;
            eT[q][4 * esf + 2][esr + 128] = en2.z;
            eT[q][4 * esf + 3][esr + 128] = en2.w;
            eT[q][4 * esf + 0][esr + 192] = en3.x;
            eT[q][4 * esf + 1][esr + 192] = en3.y;
            eT[q][4 * esf + 2][esr + 192] = en3.z;
            eT[q][4 * esf + 3][esr + 192] = en3.w;
        }

        // ---- end of k-tile: literal f32 distance + running argmin ----
        if (dcIdx == 15) {
            float4 e0 = *(const float4*)&esq[kt + 4 * cg];
            float4 e1 = *(const float4*)&esq[kt + 128 + 4 * cg];
            float es[8] = {e0.x, e0.y, e0.z, e0.w, e1.x, e1.y, e1.z, e1.w};
            #pragma unroll
            for (int j = 0; j < 16; ++j) {
                float zs = zsq_s[16 * rg + j];
                #pragma unroll
                for (int i = 0; i < 8; ++i) {
                    float t    = zs + es[i];             // fl(z_sq + e_sq)
                    float dist = t - 2.0f * acc[j][i];   // fl(t - 2*cross)
                    int idx = (i < 4) ? (kt + 4 * cg + i) : (kt + 128 + 4 * cg + (i - 4));
                    bool better = (dist < bestv[j]);
                    bestv[j] = better ? dist : bestv[j];
                    besti[j] = better ? idx  : besti[j];
                }
            }
        }
        __syncthreads();
    }

    // cross-lane argmin over the 32 code-group lanes (lexicographic: val, idx)
    #pragma unroll
    for (int off = 16; off >= 1; off >>= 1) {
        #pragma unroll
        for (int j = 0; j < 16; ++j) {
            float ov = __shfl_xor(bestv[j], off, 64);
            int   oi = __shfl_xor(besti[j], off, 64);
            bool take = (ov < bestv[j]) || (ov == bestv[j] && oi < besti[j]);
            bestv[j] = take ? ov : bestv[j];
            besti[j] = take ? oi : besti[j];
        }
    }
    if (cg == 0) {
        #pragma unroll
        for (int j = 0; j < 16; ++j) best_s[16 * rg + j] = besti[j];
    }
    __syncthreads();

    // ---- epilogue: z_q_st (straight-through), loss partial, indices ----
    float lsum = 0.f;
    const int d4 = tid & 63;
    for (int it = 0; it < 32; ++it) {
        int r  = (tid >> 6) + it * 4;
        int bk = best_s[r];
        float4 q4 = *(const float4*)&emb[(size_t)bk * DIM + 4 * d4];
        float4 z4 = *(const float4*)&z[(size_t)(m0 + r) * DIM + 4 * d4];
        float4 o;
        float dx;
        dx = q4.x - z4.x; o.x = z4.x + dx; lsum = fmaf(dx, dx, lsum);
        dx = q4.y - z4.y; o.y = z4.y + dx; lsum = fmaf(dx, dx, lsum);
        dx = q4.z - z4.z; o.z = z4.z + dx; lsum = fmaf(dx, dx, lsum);
        dx = q4.w - z4.w; o.w = z4.w + dx; lsum = fmaf(dx, dx, lsum);
        *(float4*)&out[(size_t)(m0 + r) * DIM + 4 * d4] = o;
    }
    #pragma unroll
    for (int off = 32; off >= 1; off >>= 1) lsum += __shfl_xor(lsum, off, 64);
    if ((tid & 63) == 0) lred[tid >> 6] = lsum;
    __syncthreads();
    if (tid == 0) {
        float bs = lred[0] + lred[1] + lred[2] + lred[3];
        atomicAdd(loss_acc, bs);
    }
    // indices as float32 values
    if (tid < MT) out[(size_t)N_ROWS * DIM + 1 + m0 + tid] = (float)best_s[tid];
}

// ---------------- finalize: vq_loss = 1.25 * mean ----------------
__global__ void vq_finalize_kernel(const float* __restrict__ loss_acc,
                                   float* __restrict__ out) {
    double s = (double)loss_acc[0];
    out[(size_t)N_ROWS * DIM] = (float)(s * 1.25 / ((double)N_ROWS * (double)DIM));
}

extern "C" void kernel_launch(void* const* d_in, const int* in_sizes, int n_in,
                              void* d_out, int out_size, void* d_ws, size_t ws_size,
                              hipStream_t stream) {
    (void)in_sizes; (void)n_in; (void)out_size; (void)ws_size;
    const float* z   = (const float*)d_in[0];
    const float* emb = (const float*)d_in[1];
    float* out = (float*)d_out;
    float* ws  = (float*)d_ws;
    float* loss_acc = ws;        // ws[0]
    float* esq      = ws + 64;   // 2048 floats

    hipMemsetAsync(d_ws, 0, sizeof(float), stream);
    vq_esq_kernel<<<K_CODES / 4, 256, 0, stream>>>(emb, esq);
    vq_main_kernel<<<N_ROWS / MT, BLOCK, 0, stream>>>(z, emb, esq, out, loss_acc);
    vq_finalize_kernel<<<1, 1, 0, stream>>>(loss_acc, out);
}

// Round 3
// 833.744 us; speedup vs baseline: 2.0173x; 1.3225x over previous
//
#include <hip/hip_runtime.h>
#include <cfloat>

#define N_ROWS 65536
#define DIM 256
#define K_CODES 2048
#define MT 128     // rows per block
#define KT 256     // codes per k-tile
#define DC 16      // d-chunk staged in LDS
#define BLOCK 256
#define ZSTR (MT + 4)      // 132 floats, keeps 16B align
#define ESTR (KT + 4)      // 260 floats, 16B-mult keeps b128 align
#define NSTAGES ((DIM / DC) * (K_CODES / KT))   // 128

typedef float f32x2 __attribute__((ext_vector_type(2)));
typedef float f32x4 __attribute__((ext_vector_type(4)));

#define LOHALF(v) __builtin_shufflevector(v, v, 0, 1)
#define HIHALF(v) __builtin_shufflevector(v, v, 2, 3)

// v_pk_fma_f32 with src0 broadcast from its LO / HI half via op_sel.
// D.lo = fma(sel(a), b.lo, acc.lo); D.hi = fma(sel(a), b.hi, acc.hi)
// IEEE fma per component == fmaf -> bit-identical to the scalar version.
#define PK_FMA_LO(acc, ap, bp) \
    asm("v_pk_fma_f32 %0, %1, %2, %0 op_sel:[0,0,0] op_sel_hi:[0,1,1]" \
        : "+v"(acc) : "v"(ap), "v"(bp))
#define PK_FMA_HI(acc, ap, bp) \
    asm("v_pk_fma_f32 %0, %1, %2, %0 op_sel:[1,0,0] op_sel_hi:[1,1,1]" \
        : "+v"(acc) : "v"(ap), "v"(bp))

// ---------------- e_sq precompute: one wave per code ----------------
__global__ __launch_bounds__(256)
void vq_esq_kernel(const float* __restrict__ emb, float* __restrict__ esq) {
    int w = threadIdx.x >> 6;
    int lane = threadIdx.x & 63;
    int k = blockIdx.x * 4 + w;
    float4 v = *(const float4*)&emb[(size_t)k * DIM + lane * 4];
    float s = v.x * v.x + v.y * v.y + v.z * v.z + v.w * v.w;
    #pragma unroll
    for (int off = 32; off >= 1; off >>= 1) s += __shfl_xor(s, off, 64);
    if (lane == 0) esq[k] = s;
}

// ---------------- main fused kernel (16x8 tile, pk_fma inner loop) ------
// R2 vs R1: inner product uses v_pk_fma_f32 (2 fp32 FMA per VALU issue)
// with op_sel broadcasting the z operand -> 64 pk_fma per d-step instead
// of 128 v_fma, zero extra movs. Same chain order per accumulator ->
// bit-identical distances/argmin. Everything else unchanged from R1.
__global__ __launch_bounds__(BLOCK, 1)
void vq_main_kernel(const float* __restrict__ z,
                    const float* __restrict__ emb,
                    const float* __restrict__ esq,
                    float* __restrict__ out,
                    float* __restrict__ loss_acc) {
    __shared__ float zS[2][DC][ZSTR];
    __shared__ float eT[2][DC][ESTR];
    __shared__ float zsq_s[MT];
    __shared__ int   best_s[MT];
    __shared__ float lred[4];

    const int tid = threadIdx.x;
    const int m0  = blockIdx.x * MT;
    const int rg  = tid >> 5;   // 0..7  : rows 16*rg..16*rg+15
    const int cg  = tid & 31;   // 0..31 : codes 4*cg(+128)
    const int esr = tid >> 2;   // eT staging code base (0..63)
    const int esf = tid & 3;    // eT staging float4 slot in d-chunk
    const int zr  = tid >> 1;   // zS staging row (0..127)
    const int zh  = tid & 1;    // zS staging d-half (8 floats)

    // ---- z_sq for the block's 128 rows (2 threads/row; combine tree is
    //      bit-identical to the verified kernel: (s0+s2)+(s1+s3)) ----
    {
        const float* zp = &z[(size_t)(m0 + zr) * DIM + zh * 64];
        float sA = 0.f, sB = 0.f;
        #pragma unroll
        for (int d4 = 0; d4 < 16; ++d4) {
            float4 v = *(const float4*)&zp[d4 * 4];
            sA += v.x * v.x; sA += v.y * v.y; sA += v.z * v.z; sA += v.w * v.w;
        }
        #pragma unroll
        for (int d4 = 0; d4 < 16; ++d4) {
            float4 v = *(const float4*)&zp[128 + d4 * 4];
            sB += v.x * v.x; sB += v.y * v.y; sB += v.z * v.z; sB += v.w * v.w;
        }
        float s = sA + sB;              // lane even: s0+s2, lane odd: s1+s3
        s += __shfl_down(s, 1, 64);     // (s0+s2)+(s1+s3)
        if (zh == 0) zsq_s[zr] = s;
    }

    // ---- stage 0 into buffer 0 ----
    {
        const float* zp = &z[(size_t)(m0 + zr) * DIM + 8 * zh];
        float4 za = *(const float4*)&zp[0];
        float4 zb = *(const float4*)&zp[4];
        zS[0][8 * zh + 0][zr] = za.x;
        zS[0][8 * zh + 1][zr] = za.y;
        zS[0][8 * zh + 2][zr] = za.z;
        zS[0][8 * zh + 3][zr] = za.w;
        zS[0][8 * zh + 4][zr] = zb.x;
        zS[0][8 * zh + 5][zr] = zb.y;
        zS[0][8 * zh + 6][zr] = zb.z;
        zS[0][8 * zh + 7][zr] = zb.w;
        #pragma unroll
        for (int cb = 0; cb < 4; ++cb) {
            int c = esr + cb * 64;
            float4 ev = *(const float4*)&emb[(size_t)c * DIM + 4 * esf];
            eT[0][4 * esf + 0][c] = ev.x;
            eT[0][4 * esf + 1][c] = ev.y;
            eT[0][4 * esf + 2][c] = ev.z;
            eT[0][4 * esf + 3][c] = ev.w;
        }
    }
    __syncthreads();

    float bestv[16];
    int   besti[16];
    #pragma unroll
    for (int j = 0; j < 16; ++j) { bestv[j] = FLT_MAX; besti[j] = 0; }

    f32x2 acc2[16][4];

    for (int s = 0; s < NSTAGES; ++s) {
        const int p     = s & 1;
        const int kt    = (s >> 4) * KT;
        const int dcIdx = s & 15;

        if (dcIdx == 0) {
            #pragma unroll
            for (int j = 0; j < 16; ++j)
                #pragma unroll
                for (int i2 = 0; i2 < 4; ++i2) acc2[j][i2] = (f32x2){0.f, 0.f};
        }

        // ---- prefetch stage s+1 (global -> regs); uniform clamp on last ----
        const int sn  = (s + 1 < NSTAGES) ? s + 1 : s;
        const int nkt = (sn >> 4) * KT;
        const int ndc = (sn & 15) * DC;
        float4 zn0 = *(const float4*)&z[(size_t)(m0 + zr) * DIM + ndc + 8 * zh];
        float4 zn1 = *(const float4*)&z[(size_t)(m0 + zr) * DIM + ndc + 8 * zh + 4];
        float4 en0 = *(const float4*)&emb[(size_t)(nkt + esr +   0) * DIM + ndc + 4 * esf];
        float4 en1 = *(const float4*)&emb[(size_t)(nkt + esr +  64) * DIM + ndc + 4 * esf];
        float4 en2 = *(const float4*)&emb[(size_t)(nkt + esr + 128) * DIM + ndc + 4 * esf];
        float4 en3 = *(const float4*)&emb[(size_t)(nkt + esr + 192) * DIM + ndc + 4 * esf];

        // ---- compute stage s: 64 v_pk_fma_f32 per d-step ----
        #pragma unroll
        for (int d = 0; d < DC; ++d) {
            f32x4 a0 = *(const f32x4*)&zS[p][d][16 * rg];
            f32x4 a1 = *(const f32x4*)&zS[p][d][16 * rg + 4];
            f32x4 a2 = *(const f32x4*)&zS[p][d][16 * rg + 8];
            f32x4 a3 = *(const f32x4*)&zS[p][d][16 * rg + 12];
            f32x4 b0 = *(const f32x4*)&eT[p][d][4 * cg];
            f32x4 b1 = *(const f32x4*)&eT[p][d][128 + 4 * cg];
            f32x2 ap[8] = { LOHALF(a0), HIHALF(a0), LOHALF(a1), HIHALF(a1),
                            LOHALF(a2), HIHALF(a2), LOHALF(a3), HIHALF(a3) };
            f32x2 bp[4] = { LOHALF(b0), HIHALF(b0), LOHALF(b1), HIHALF(b1) };
            #pragma unroll
            for (int jp = 0; jp < 8; ++jp) {
                #pragma unroll
                for (int i2 = 0; i2 < 4; ++i2) {
                    PK_FMA_LO(acc2[2 * jp][i2],     ap[jp], bp[i2]);
                    PK_FMA_HI(acc2[2 * jp + 1][i2], ap[jp], bp[i2]);
                }
            }
        }

        // ---- write prefetched stage into the other buffer ----
        {
            const int q = p ^ 1;
            zS[q][8 * zh + 0][zr] = zn0.x;
            zS[q][8 * zh + 1][zr] = zn0.y;
            zS[q][8 * zh + 2][zr] = zn0.z;
            zS[q][8 * zh + 3][zr] = zn0.w;
            zS[q][8 * zh + 4][zr] = zn1.x;
            zS[q][8 * zh + 5][zr] = zn1.y;
            zS[q][8 * zh + 6][zr] = zn1.z;
            zS[q][8 * zh + 7][zr] = zn1.w;
            eT[q][4 * esf + 0][esr      ] = en0.x;
            eT[q][4 * esf + 1][esr      ] = en0.y;
            eT[q][4 * esf + 2][esr      ] = en0.z;
            eT[q][4 * esf + 3][esr      ] = en0.w;
            eT[q][4 * esf + 0][esr +  64] = en1.x;
            eT[q][4 * esf + 1][esr +  64] = en1.y;
            eT[q][4 * esf + 2][esr +  64] = en1.z;
            eT[q][4 * esf + 3][esr +  64] = en1.w;
            eT[q][4 * esf + 0][esr + 128] = en2.x;
            eT[q][4 * esf + 1][esr + 128] = en2.y;
            eT[q][4 * esf + 2][esr + 128] = en2.z;
            eT[q][4 * esf + 3][esr + 128] = en2.w;
            eT[q][4 * esf + 0][esr + 192] = en3.x;
            eT[q][4 * esf + 1][esr + 192] = en3.y;
            eT[q][4 * esf + 2][esr + 192] = en3.z;
            eT[q][4 * esf + 3][esr + 192] = en3.w;
        }

        // ---- end of k-tile: literal f32 distance + running argmin ----
        if (dcIdx == 15) {
            float4 e0 = *(const float4*)&esq[kt + 4 * cg];
            float4 e1 = *(const float4*)&esq[kt + 128 + 4 * cg];
            float es[8] = {e0.x, e0.y, e0.z, e0.w, e1.x, e1.y, e1.z, e1.w};
            #pragma unroll
            for (int j = 0; j < 16; ++j) {
                float zs = zsq_s[16 * rg + j];
                #pragma unroll
                for (int i = 0; i < 8; ++i) {
                    float aij  = acc2[j][i >> 1][i & 1];
                    float t    = zs + es[i];             // fl(z_sq + e_sq)
                    float dist = t - 2.0f * aij;         // fl(t - 2*cross)
                    int idx = (i < 4) ? (kt + 4 * cg + i) : (kt + 128 + 4 * cg + (i - 4));
                    bool better = (dist < bestv[j]);
                    bestv[j] = better ? dist : bestv[j];
                    besti[j] = better ? idx  : besti[j];
                }
            }
        }
        __syncthreads();
    }

    // cross-lane argmin over the 32 code-group lanes (lexicographic: val, idx)
    #pragma unroll
    for (int off = 16; off >= 1; off >>= 1) {
        #pragma unroll
        for (int j = 0; j < 16; ++j) {
            float ov = __shfl_xor(bestv[j], off, 64);
            int   oi = __shfl_xor(besti[j], off, 64);
            bool take = (ov < bestv[j]) || (ov == bestv[j] && oi < besti[j]);
            bestv[j] = take ? ov : bestv[j];
            besti[j] = take ? oi : besti[j];
        }
    }
    if (cg == 0) {
        #pragma unroll
        for (int j = 0; j < 16; ++j) best_s[16 * rg + j] = besti[j];
    }
    __syncthreads();

    // ---- epilogue: z_q_st (straight-through), loss partial, indices ----
    float lsum = 0.f;
    const int d4 = tid & 63;
    for (int it = 0; it < 32; ++it) {
        int r  = (tid >> 6) + it * 4;
        int bk = best_s[r];
        float4 q4 = *(const float4*)&emb[(size_t)bk * DIM + 4 * d4];
        float4 z4 = *(const float4*)&z[(size_t)(m0 + r) * DIM + 4 * d4];
        float4 o;
        float dx;
        dx = q4.x - z4.x; o.x = z4.x + dx; lsum = fmaf(dx, dx, lsum);
        dx = q4.y - z4.y; o.y = z4.y + dx; lsum = fmaf(dx, dx, lsum);
        dx = q4.z - z4.z; o.z = z4.z + dx; lsum = fmaf(dx, dx, lsum);
        dx = q4.w - z4.w; o.w = z4.w + dx; lsum = fmaf(dx, dx, lsum);
        *(float4*)&out[(size_t)(m0 + r) * DIM + 4 * d4] = o;
    }
    #pragma unroll
    for (int off = 32; off >= 1; off >>= 1) lsum += __shfl_xor(lsum, off, 64);
    if ((tid & 63) == 0) lred[tid >> 6] = lsum;
    __syncthreads();
    if (tid == 0) {
        float bs = lred[0] + lred[1] + lred[2] + lred[3];
        atomicAdd(loss_acc, bs);
    }
    // indices as float32 values
    if (tid < MT) out[(size_t)N_ROWS * DIM + 1 + m0 + tid] = (float)best_s[tid];
}

// ---------------- finalize: vq_loss = 1.25 * mean ----------------
__global__ void vq_finalize_kernel(const float* __restrict__ loss_acc,
                                   float* __restrict__ out) {
    double s = (double)loss_acc[0];
    out[(size_t)N_ROWS * DIM] = (float)(s * 1.25 / ((double)N_ROWS * (double)DIM));
}

extern "C" void kernel_launch(void* const* d_in, const int* in_sizes, int n_in,
                              void* d_out, int out_size, void* d_ws, size_t ws_size,
                              hipStream_t stream) {
    (void)in_sizes; (void)n_in; (void)out_size; (void)ws_size;
    const float* z   = (const float*)d_in[0];
    const float* emb = (const float*)d_in[1];
    float* out = (float*)d_out;
    float* ws  = (float*)d_ws;
    float* loss_acc = ws;        // ws[0]
    float* esq      = ws + 64;   // 2048 floats

    hipMemsetAsync(d_ws, 0, sizeof(float), stream);
    vq_esq_kernel<<<K_CODES / 4, 256, 0, stream>>>(emb, esq);
    vq_main_kernel<<<N_ROWS / MT, BLOCK, 0, stream>>>(z, emb, esq, out, loss_acc);
    vq_finalize_kernel<<<1, 1, 0, stream>>>(loss_acc, out);
}